// Round 13
// baseline (640.140 us; speedup 1.0000x reference)
//
#include <hip/hip_runtime.h>

#define N_TOK 8192
#define DIM   2048
#define HID   2048
#define NE    8
#define BK    64
#define NKT   (DIM / BK)

typedef unsigned short u16;
typedef __attribute__((ext_vector_type(4))) float f4v;
typedef __attribute__((ext_vector_type(8))) short s8v;

__device__ __forceinline__ unsigned int cvtpk(float lo, float hi) {
  unsigned int r;
  asm volatile("v_cvt_pk_bf16_f32 %0, %1, %2" : "=v"(r) : "v"(lo), "v"(hi));
  return r;
}
#define BAR()  asm volatile("s_barrier" ::: "memory")
#define LGKM0() asm volatile("s_waitcnt lgkmcnt(0)" ::: "memory")

// ---------------- gating: logits -> softmax -> top2 (NO atomics) ----------------
__global__ __launch_bounds__(256) void gating_kernel(
    const float* __restrict__ x, const float* __restrict__ Wg,
    const float* __restrict__ bg, int* __restrict__ sel,
    float* __restrict__ wslot)
{
  __shared__ float wg_lds[NE][DIM];   // 64 KB
  #pragma unroll
  for (int i = 0; i < 16; ++i) {
    int f = threadIdx.x + 256 * i;          // float4 index 0..4095
    int d = f >> 1, ep = (f & 1) * 4;
    float4 w = reinterpret_cast<const float4*>(Wg)[f];
    wg_lds[ep + 0][d] = w.x; wg_lds[ep + 1][d] = w.y;
    wg_lds[ep + 2][d] = w.z; wg_lds[ep + 3][d] = w.w;
  }
  __syncthreads();

  int wave = threadIdx.x >> 6, lane = threadIdx.x & 63;
  #pragma unroll 2
  for (int j = 0; j < 4; ++j) {
    int n = blockIdx.x * 16 + wave * 4 + j;
    const float4* x4 = reinterpret_cast<const float4*>(x + (size_t)n * DIM);
    float acc[NE] = {0.f,0.f,0.f,0.f,0.f,0.f,0.f,0.f};
    #pragma unroll
    for (int i = 0; i < 8; ++i) {
      int d4 = lane + 64 * i;
      float4 xv = x4[d4];
      #pragma unroll
      for (int e = 0; e < NE; ++e) {
        float4 w = *reinterpret_cast<const float4*>(&wg_lds[e][d4 * 4]);
        acc[e] += xv.x * w.x + xv.y * w.y + xv.z * w.z + xv.w * w.w;
      }
    }
    #pragma unroll
    for (int e = 0; e < NE; ++e)
      #pragma unroll
      for (int off = 32; off; off >>= 1)
        acc[e] += __shfl_xor(acc[e], off);

    if (lane == 0) {
      float m = -1e30f;
      #pragma unroll
      for (int e = 0; e < NE; ++e) { acc[e] += bg[e]; m = fmaxf(m, acc[e]); }
      float p[NE]; float s = 0.f;
      #pragma unroll
      for (int e = 0; e < NE; ++e) { p[e] = expf(acc[e] - m); s += p[e]; }
      float inv = 1.0f / s;
      int e1 = 0; float v1 = p[0];
      #pragma unroll
      for (int e = 1; e < NE; ++e) if (p[e] > v1) { v1 = p[e]; e1 = e; }
      int e2 = -1; float v2 = -1.f;
      #pragma unroll
      for (int e = 0; e < NE; ++e) if (e != e1 && p[e] > v2) { v2 = p[e]; e2 = e; }
      sel[n] = e1 | (e2 << 4);
      wslot[n] = v1 * inv;
      wslot[N_TOK + n] = v2 * inv;
    }
  }
}

// ---------------- build per-(slot,expert) token lists: deterministic compaction ----------------
__global__ __launch_bounds__(256) void build_lists_kernel(
    const int* __restrict__ sel, int* __restrict__ counts, int* __restrict__ lists)
{
  __shared__ int wsum[4];
  __shared__ int runbase;
  int b = blockIdx.x;           // 0..15: slot = b>>3, expert = b&7
  int s = b >> 3, e = b & 7;
  int t = threadIdx.x, lane = t & 63, wave = t >> 6;
  if (t == 0) runbase = 0;
  __syncthreads();
  int* listp = lists + (size_t)b * N_TOK;
  for (int base = 0; base < N_TOK; base += 256) {
    int n = base + t;
    int sv = sel[n];
    int field = s ? (sv >> 4) : (sv & 15);
    bool p = (field == e);
    unsigned long long mask = __ballot(p);
    int rank = __popcll(mask & ((1ull << lane) - 1ull));
    int wtot = __popcll(mask);
    if (lane == 0) wsum[wave] = wtot;
    __syncthreads();
    int wbase = 0;
    #pragma unroll
    for (int w = 0; w < 4; ++w) wbase += (w < wave) ? wsum[w] : 0;
    int tot = wsum[0] + wsum[1] + wsum[2] + wsum[3];
    if (p) listp[runbase + wbase + rank] = n;
    __syncthreads();
    if (t == 0) runbase += tot;
    __syncthreads();
  }
  if (t == 0) counts[b] = runbase;
}

// ---------------- build compact tile descriptors ----------------
__global__ void build_desc_kernel(const int* __restrict__ counts,
                                  int* __restrict__ gfirst, int* __restrict__ desc)
{
  if (threadIdx.x == 0 && blockIdx.x == 0) {
    for (int s = 0; s < 2; ++s) {
      int tc = 0;
      for (int e = 0; e < NE; ++e) {
        gfirst[s * 9 + e] = tc;
        int nt = (counts[s * NE + e] + 127) >> 7;
        for (int i = 0; i < nt; ++i) desc[s * 71 + tc++] = (e << 8) | i;
      }
      gfirst[s * 9 + 8] = tc;
    }
  }
}

// ---------------- GEMM: producer/consumer wave specialization ----------------
// 512 threads = 8 waves. Waves 0-3 stage (R3's exact patterns, dual reg-set,
// LDS double-buffer). Waves 4-7 do MFMA only (never issue VMEM -> no vmcnt drain).
// One raw s_barrier per kt; producers wait lgkmcnt(0) only.
template <int PHASE>
__global__ __launch_bounds__(512) void moe_gemm_f32(
    const float* __restrict__ xf, const float* __restrict__ Wef,
    const float* __restrict__ be, const int* __restrict__ counts,
    const int* __restrict__ gfirst, const int* __restrict__ desc,
    const int* __restrict__ lists, const float* __restrict__ wslot,
    float* __restrict__ out)
{
  __shared__ __align__(16) u16 A_lds[2][128 * 64];   // 32 KB bf16 [m][k]
  __shared__ __align__(16) u16 B_lds[2][128 * 64];   // 32 KB bf16 [n][k]
  __shared__ int   tok_lds[128];
  __shared__ float wgt_lds[128];

  const int ntile = blockIdx.x;          // 0..15 (fastest: R3 L2 locality)
  const int idx   = blockIdx.y;          // 0..70
  if (idx >= gfirst[PHASE * 9 + 8]) return;
  const int d  = desc[PHASE * 71 + idx];
  const int e  = d >> 8;
  const int mt = d & 255;
  const int cnt = counts[PHASE * NE + e];

  const int t = threadIdx.x;
  if (t < 128) {
    int r = mt * 128 + t;
    int rc = (r < cnt) ? r : (cnt - 1);
    int tok = lists[(PHASE * NE + e) * N_TOK + rc];
    tok_lds[t] = tok;
    wgt_lds[t] = wslot[PHASE * N_TOK + tok];
  }
  __syncthreads();   // safe: no outstanding VMEM yet

  const int lane = t & 63, wid = t >> 6;
  const float* wef = Wef + (size_t)e * DIM * HID;

  if (wid < 4) {
    // ================= PRODUCER (256 threads, R3 staging patterns) =================
    const int p = t;                       // 0..255
    // A: 8 (row, 16B-chunk) slots
    size_t aoff[8]; unsigned int ab[8];
    #pragma unroll
    for (int i = 0; i < 8; ++i) {
      int flat = p + 256 * i;              // 0..2047
      int row = flat >> 4, c4 = flat & 15;
      aoff[i] = (size_t)tok_lds[row] * DIM + c4 * 4;
      ab[i] = ((unsigned int)(row * 128 + c4 * 8)) ^ (((unsigned int)row & 7u) << 4);
    }
    // B: 32 scalar column loads; bn = col, bh in {0,1} k-half
    const int bn = p & 127, bh = p >> 7;
    const float* bp0 = wef + (size_t)(bh * 32) * HID + ntile * 128 + bn;
    unsigned int bbyte[8];
    #pragma unroll
    for (int kb = 0; kb < 8; ++kb)
      bbyte[kb] = ((unsigned int)(bn * 128 + bh * 64 + kb * 8)) ^ (((unsigned int)bn & 7u) << 4);

    float4 av0[8], av1[8];
    float  bv0[32], bv1[32];

#define P_ISSUE(AV, BV, KT) do {                                                  \
    _Pragma("unroll") for (int i = 0; i < 8; ++i)                                 \
      AV[i] = *reinterpret_cast<const float4*>(xf + aoff[i] + (KT) * 64);         \
    const float* bpk = bp0 + (size_t)(KT) * 64 * HID;                             \
    _Pragma("unroll") for (int j = 0; j < 32; ++j)                                \
      BV[j] = bpk[(size_t)j * HID];                                               \
  } while (0)
#define P_WRITE(AV, BV, BUF) do {                                                 \
    char* abase = reinterpret_cast<char*>(&A_lds[BUF][0]);                        \
    char* bbase = reinterpret_cast<char*>(&B_lds[BUF][0]);                        \
    _Pragma("unroll") for (int i = 0; i < 8; ++i) {                               \
      uint2 w; w.x = cvtpk(AV[i].x, AV[i].y); w.y = cvtpk(AV[i].z, AV[i].w);      \
      *reinterpret_cast<uint2*>(abase + ab[i]) = w;                               \
    }                                                                             \
    _Pragma("unroll") for (int kb = 0; kb < 8; ++kb) {                            \
      uint2 w; w.x = cvtpk(BV[kb*4+0], BV[kb*4+1]);                               \
               w.y = cvtpk(BV[kb*4+2], BV[kb*4+3]);                               \
      *reinterpret_cast<uint2*>(bbase + bbyte[kb]) = w;                           \
    }                                                                             \
  } while (0)

    P_ISSUE(av0, bv0, 0);        // set0 = even kts
    P_ISSUE(av1, bv1, 1);        // set1 = odd kts
    P_WRITE(av0, bv0, 0);        // buf0 ready (vmcnt waits set0 only)
    LGKM0();

    #pragma unroll 1
    for (int kt = 0; kt < NKT; ++kt) {
      BAR();                                     // buf[kt&1] visible to consumers
      if (kt & 1) {
        if (kt + 1 < NKT) P_WRITE(av0, bv0, 0);  // kt+1 even -> set0 -> buf0
        if (kt + 2 < NKT) P_ISSUE(av1, bv1, kt + 2);
      } else {
        if (kt + 1 < NKT) P_WRITE(av1, bv1, 1);  // kt+1 odd -> set1 -> buf1
        if (kt + 2 < NKT) P_ISSUE(av0, bv0, kt + 2);
      }
      LGKM0();                                   // ds_writes visible before next BAR
    }
#undef P_ISSUE
#undef P_WRITE
    return;   // producers exit; no more barriers on either path
  }

  // ================= CONSUMER (waves 4-7, MFMA only) =================
  const int cw = wid - 4;
  const int wm = (cw & 1) * 64, wn = (cw >> 1) * 64;
  const int lrow = lane & 15, lkg = lane >> 4;

  f4v acc[4][4];
  f4v zero = {0.f, 0.f, 0.f, 0.f};
  #pragma unroll
  for (int mi = 0; mi < 4; ++mi)
    #pragma unroll
    for (int ni = 0; ni < 4; ++ni) acc[mi][ni] = zero;

  #pragma unroll 1
  for (int kt = 0; kt < NKT; ++kt) {
    BAR();
    const u16* Ab = &A_lds[kt & 1][0];
    const u16* Bb = &B_lds[kt & 1][0];
    #pragma unroll
    for (int kk2 = 0; kk2 < 2; ++kk2) {
      s8v a[4], b[4];
      unsigned int koff = (unsigned int)(kk2 * 64 + lkg * 16);
      #pragma unroll
      for (int i = 0; i < 4; ++i) {
        unsigned int arow = (unsigned int)(wm + i * 16 + lrow);
        a[i] = *reinterpret_cast<const s8v*>(
            reinterpret_cast<const char*>(Ab) + ((arow * 128u + koff) ^ ((arow & 7u) << 4)));
        unsigned int brow = (unsigned int)(wn + i * 16 + lrow);
        b[i] = *reinterpret_cast<const s8v*>(
            reinterpret_cast<const char*>(Bb) + ((brow * 128u + koff) ^ ((brow & 7u) << 4)));
      }
      #pragma unroll
      for (int mi = 0; mi < 4; ++mi)
        #pragma unroll
        for (int ni = 0; ni < 4; ++ni)
          acc[mi][ni] = __builtin_amdgcn_mfma_f32_16x16x32_bf16(a[mi], b[ni], acc[mi][ni], 0, 0, 0);
    }
  }

  // epilogue: D row=(lane>>4)*4+q (A/m), col=lane&15 (B/n)  [m89-verified]
  const float* bev = be + (size_t)e * HID + ntile * 128;
  #pragma unroll
  for (int ni = 0; ni < 4; ++ni) {
    int col = wn + ni * 16 + lrow;
    float bevv = bev[col];
    #pragma unroll
    for (int mi = 0; mi < 4; ++mi) {
      #pragma unroll
      for (int q = 0; q < 4; ++q) {
        int row = wm + mi * 16 + lkg * 4 + q;
        if (mt * 128 + row < cnt) {
          int tok = tok_lds[row];
          float w = wgt_lds[row];
          float v = w * (acc[mi][ni][q] + bevv);
          float* o = out + (size_t)tok * HID + ntile * 128 + col;
          if (PHASE == 0) *o = v; else *o += v;
        }
      }
    }
  }
}

// ---------------- host ----------------
extern "C" void kernel_launch(void* const* d_in, const int* in_sizes, int n_in,
                              void* d_out, int out_size, void* d_ws, size_t ws_size,
                              hipStream_t stream) {
  const float* x  = (const float*)d_in[0];
  const float* Wg = (const float*)d_in[1];
  const float* bg = (const float*)d_in[2];
  const float* We = (const float*)d_in[3];
  const float* be = (const float*)d_in[4];
  float* out = (float*)d_out;
  char* ws = (char*)d_ws;

  int*   counts = (int*)ws;                         // 16 ints @0
  int*   gfirst = (int*)(ws + 64);                  // 18 ints
  int*   desc   = (int*)(ws + 256);                 // 142 ints
  int*   sel    = (int*)(ws + 1024);                // 8192 ints
  float* wslot  = (float*)(ws + 33792);             // 16384 f32
  int*   lists  = (int*)(ws + 99328);               // 2*8*8192 ints -> end 623616

  hipLaunchKernelGGL(gating_kernel, dim3(512), dim3(256), 0, stream,
                     x, Wg, bg, sel, wslot);
  hipLaunchKernelGGL(build_lists_kernel, dim3(16), dim3(256), 0, stream,
                     sel, counts, lists);
  hipLaunchKernelGGL(build_desc_kernel, dim3(1), dim3(64), 0, stream,
                     counts, gfirst, desc);

  dim3 ggrid(16, 71);   // x = ntile fastest: R3 L2 locality
  hipLaunchKernelGGL((moe_gemm_f32<0>), ggrid, dim3(512), 0, stream,
                     x, We, be, counts, gfirst, desc, lists, wslot, out);
  hipLaunchKernelGGL((moe_gemm_f32<1>), ggrid, dim3(512), 0, stream,
                     x, We, be, counts, gfirst, desc, lists, wslot, out);
}

// Round 14
// 552.278 us; speedup vs baseline: 1.1591x; 1.1591x over previous
//
#include <hip/hip_runtime.h>

#define N_TOK 8192
#define DIM   2048
#define HID   2048
#define NE    8
#define BK    64
#define NKT   (DIM / BK)

typedef unsigned short u16;
typedef __attribute__((ext_vector_type(4))) float f4v;
typedef __attribute__((ext_vector_type(8))) short s8v;

__device__ __forceinline__ unsigned int cvtpk(float lo, float hi) {
  unsigned int r;
  asm volatile("v_cvt_pk_bf16_f32 %0, %1, %2" : "=v"(r) : "v"(lo), "v"(hi));
  return r;
}

// ---------------- gating: logits -> softmax -> top2 (NO atomics) ----------------
__global__ __launch_bounds__(256) void gating_kernel(
    const float* __restrict__ x, const float* __restrict__ Wg,
    const float* __restrict__ bg, int* __restrict__ sel,
    float* __restrict__ wslot)
{
  __shared__ float wg_lds[NE][DIM];   // 64 KB
  #pragma unroll
  for (int i = 0; i < 16; ++i) {
    int f = threadIdx.x + 256 * i;          // float4 index 0..4095
    int d = f >> 1, ep = (f & 1) * 4;
    float4 w = reinterpret_cast<const float4*>(Wg)[f];
    wg_lds[ep + 0][d] = w.x; wg_lds[ep + 1][d] = w.y;
    wg_lds[ep + 2][d] = w.z; wg_lds[ep + 3][d] = w.w;
  }
  __syncthreads();

  int wave = threadIdx.x >> 6, lane = threadIdx.x & 63;
  #pragma unroll 2
  for (int j = 0; j < 4; ++j) {
    int n = blockIdx.x * 16 + wave * 4 + j;
    const float4* x4 = reinterpret_cast<const float4*>(x + (size_t)n * DIM);
    float acc[NE] = {0.f,0.f,0.f,0.f,0.f,0.f,0.f,0.f};
    #pragma unroll
    for (int i = 0; i < 8; ++i) {
      int d4 = lane + 64 * i;
      float4 xv = x4[d4];
      #pragma unroll
      for (int e = 0; e < NE; ++e) {
        float4 w = *reinterpret_cast<const float4*>(&wg_lds[e][d4 * 4]);
        acc[e] += xv.x * w.x + xv.y * w.y + xv.z * w.z + xv.w * w.w;
      }
    }
    #pragma unroll
    for (int e = 0; e < NE; ++e)
      #pragma unroll
      for (int off = 32; off; off >>= 1)
        acc[e] += __shfl_xor(acc[e], off);

    if (lane == 0) {
      float m = -1e30f;
      #pragma unroll
      for (int e = 0; e < NE; ++e) { acc[e] += bg[e]; m = fmaxf(m, acc[e]); }
      float p[NE]; float s = 0.f;
      #pragma unroll
      for (int e = 0; e < NE; ++e) { p[e] = expf(acc[e] - m); s += p[e]; }
      float inv = 1.0f / s;
      int e1 = 0; float v1 = p[0];
      #pragma unroll
      for (int e = 1; e < NE; ++e) if (p[e] > v1) { v1 = p[e]; e1 = e; }
      int e2 = -1; float v2 = -1.f;
      #pragma unroll
      for (int e = 0; e < NE; ++e) if (e != e1 && p[e] > v2) { v2 = p[e]; e2 = e; }
      sel[n] = e1 | (e2 << 4);
      wslot[n] = v1 * inv;
      wslot[N_TOK + n] = v2 * inv;
    }
  }
}

// ---------------- build per-(slot,expert) token lists: deterministic compaction ----------------
__global__ __launch_bounds__(256) void build_lists_kernel(
    const int* __restrict__ sel, int* __restrict__ counts, int* __restrict__ lists)
{
  __shared__ int wsum[4];
  __shared__ int runbase;
  int b = blockIdx.x;           // 0..15: slot = b>>3, expert = b&7
  int s = b >> 3, e = b & 7;
  int t = threadIdx.x, lane = t & 63, wave = t >> 6;
  if (t == 0) runbase = 0;
  __syncthreads();
  int* listp = lists + (size_t)b * N_TOK;
  for (int base = 0; base < N_TOK; base += 256) {
    int n = base + t;
    int sv = sel[n];
    int field = s ? (sv >> 4) : (sv & 15);
    bool p = (field == e);
    unsigned long long mask = __ballot(p);
    int rank = __popcll(mask & ((1ull << lane) - 1ull));
    int wtot = __popcll(mask);
    if (lane == 0) wsum[wave] = wtot;
    __syncthreads();
    int wbase = 0;
    #pragma unroll
    for (int w = 0; w < 4; ++w) wbase += (w < wave) ? wsum[w] : 0;
    int tot = wsum[0] + wsum[1] + wsum[2] + wsum[3];
    if (p) listp[runbase + wbase + rank] = n;
    __syncthreads();
    if (t == 0) runbase += tot;
    __syncthreads();
  }
  if (t == 0) counts[b] = runbase;
}

// ---------------- build compact tile descriptors (256-row tiles) ----------------
__global__ void build_desc_kernel(const int* __restrict__ counts,
                                  int* __restrict__ gfirst, int* __restrict__ desc)
{
  if (threadIdx.x == 0 && blockIdx.x == 0) {
    for (int s = 0; s < 2; ++s) {
      int tc = 0;
      for (int e = 0; e < NE; ++e) {
        gfirst[s * 9 + e] = tc;
        int nt = (counts[s * NE + e] + 255) >> 8;
        for (int i = 0; i < nt; ++i) desc[s * 71 + tc++] = (e << 8) | i;
      }
      gfirst[s * 9 + 8] = tc;
    }
  }
}

// ---------------- GEMM: 256x256 tile, R3 skeleton, 512 threads / 8 waves ----------------
// Demand-bytes halved vs 128^2: ~288 blocks x 4MB instead of 1136 x 2MB.
template <int PHASE>
__global__ __launch_bounds__(512) void moe_gemm_f32(
    const float* __restrict__ xf, const float* __restrict__ Wef,
    const float* __restrict__ be, const int* __restrict__ counts,
    const int* __restrict__ gfirst, const int* __restrict__ desc,
    const int* __restrict__ lists, const float* __restrict__ wslot,
    float* __restrict__ out)
{
  __shared__ __align__(16) u16 A_lds[256 * BK];   // 32 KB bf16 [m][k]
  __shared__ __align__(16) u16 B_lds[256 * BK];   // 32 KB bf16 [n][k]
  __shared__ int   tok_lds[256];
  __shared__ float wgt_lds[256];

  const int ntile = blockIdx.x;          // 0..7 (fastest: blocks of same idx share A-tile)
  const int idx   = blockIdx.y;          // 0..38
  if (idx >= gfirst[PHASE * 9 + 8]) return;
  const int d  = desc[PHASE * 71 + idx];
  const int e  = d >> 8;
  const int mt = d & 255;                // 256-row tile index
  const int cnt = counts[PHASE * NE + e];

  const int t = threadIdx.x;
  if (t < 256) {
    int r = mt * 256 + t;
    int rc = (r < cnt) ? r : (cnt - 1);
    int tok = lists[(PHASE * NE + e) * N_TOK + rc];
    tok_lds[t] = tok;
    wgt_lds[t] = wslot[PHASE * N_TOK + tok];
  }
  __syncthreads();

  const int lane = t & 63, wid = t >> 6;         // wid 0..7
  const int wm = (wid & 1) * 128, wn = (wid >> 1) * 64;
  const int lrow = lane & 15, lkg = lane >> 4;

  f4v acc[8][4];
  f4v zero = {0.f, 0.f, 0.f, 0.f};
  #pragma unroll
  for (int mi = 0; mi < 8; ++mi)
    #pragma unroll
    for (int ni = 0; ni < 4; ++ni) acc[mi][ni] = zero;

  const float* wef = Wef + (size_t)e * DIM * HID;

  // A: 8 (row, 16B-chunk) slots per thread over 256 rows x 16 chunks (R3 pattern)
  unsigned int aoff[8]; unsigned int ab[8];
  #pragma unroll
  for (int i = 0; i < 8; ++i) {
    int flat = t + 512 * i;              // 0..4095
    int row = flat >> 4, c4 = flat & 15;
    aoff[i] = (unsigned int)(tok_lds[row] * DIM + c4 * 4);
    ab[i] = ((unsigned int)(row * 128 + c4 * 8)) ^ (((unsigned int)row & 7u) << 4);
  }
  // B: 32 scalar column loads per thread; bn = col (0..255), bh = k-half (0..1)
  const int bn = t & 255, bh = t >> 8;
  const float* bp0 = wef + (size_t)(bh * 32) * HID + ntile * 256 + bn;
  unsigned int bbyte[8];
  #pragma unroll
  for (int kb = 0; kb < 8; ++kb)
    bbyte[kb] = ((unsigned int)(bn * 128 + bh * 64 + kb * 8)) ^ (((unsigned int)bn & 7u) << 4);

  #pragma unroll 1
  for (int kt = 0; kt < NKT; ++kt) {
    // ---- load slab into regs ----
    float4 av[8];
    #pragma unroll
    for (int i = 0; i < 8; ++i)
      av[i] = *reinterpret_cast<const float4*>(xf + aoff[i] + kt * BK);
    float bv[32];
    const float* bpk = bp0 + (size_t)kt * BK * HID;
    #pragma unroll
    for (int j = 0; j < 32; ++j)
      bv[j] = bpk[(size_t)j * HID];

    // ---- A -> LDS ----
    #pragma unroll
    for (int i = 0; i < 8; ++i) {
      uint2 w; w.x = cvtpk(av[i].x, av[i].y); w.y = cvtpk(av[i].z, av[i].w);
      *reinterpret_cast<uint2*>(reinterpret_cast<char*>(A_lds) + ab[i]) = w;
    }
    // ---- B -> LDS ----
    #pragma unroll
    for (int kb = 0; kb < 8; ++kb) {
      uint2 w; w.x = cvtpk(bv[kb * 4 + 0], bv[kb * 4 + 1]);
               w.y = cvtpk(bv[kb * 4 + 2], bv[kb * 4 + 3]);
      *reinterpret_cast<uint2*>(reinterpret_cast<char*>(B_lds) + bbyte[kb]) = w;
    }
    __syncthreads();
    // ---- mma: 2 kk-steps x (4 b-frags staged, 8 m-frags streamed) = 64 MFMA ----
    #pragma unroll
    for (int kk2 = 0; kk2 < 2; ++kk2) {
      unsigned int koff = (unsigned int)(kk2 * 64 + lkg * 16);
      s8v b[4];
      #pragma unroll
      for (int ni = 0; ni < 4; ++ni) {
        unsigned int brow = (unsigned int)(wn + ni * 16 + lrow);
        b[ni] = *reinterpret_cast<const s8v*>(
            reinterpret_cast<const char*>(B_lds) + ((brow * 128u + koff) ^ ((brow & 7u) << 4)));
      }
      #pragma unroll
      for (int mi = 0; mi < 8; ++mi) {
        unsigned int arow = (unsigned int)(wm + mi * 16 + lrow);
        s8v a = *reinterpret_cast<const s8v*>(
            reinterpret_cast<const char*>(A_lds) + ((arow * 128u + koff) ^ ((arow & 7u) << 4)));
        #pragma unroll
        for (int ni = 0; ni < 4; ++ni)
          acc[mi][ni] = __builtin_amdgcn_mfma_f32_16x16x32_bf16(a, b[ni], acc[mi][ni], 0, 0, 0);
      }
    }
    __syncthreads();
  }

  // epilogue: D row=(lane>>4)*4+q (A/m), col=lane&15 (B/n)  [m89-verified]
  const float* bev = be + (size_t)e * HID + ntile * 256;
  #pragma unroll
  for (int ni = 0; ni < 4; ++ni) {
    int col = wn + ni * 16 + lrow;
    float bevv = bev[col];
    #pragma unroll
    for (int mi = 0; mi < 8; ++mi) {
      #pragma unroll
      for (int q = 0; q < 4; ++q) {
        int row = wm + mi * 16 + lkg * 4 + q;
        if (mt * 256 + row < cnt) {
          int tok = tok_lds[row];
          float w = wgt_lds[row];
          float v = w * (acc[mi][ni][q] + bevv);
          float* o = out + (size_t)tok * HID + ntile * 256 + col;
          if (PHASE == 0) *o = v; else *o += v;
        }
      }
    }
  }
}

// ---------------- host ----------------
extern "C" void kernel_launch(void* const* d_in, const int* in_sizes, int n_in,
                              void* d_out, int out_size, void* d_ws, size_t ws_size,
                              hipStream_t stream) {
  const float* x  = (const float*)d_in[0];
  const float* Wg = (const float*)d_in[1];
  const float* bg = (const float*)d_in[2];
  const float* We = (const float*)d_in[3];
  const float* be = (const float*)d_in[4];
  float* out = (float*)d_out;
  char* ws = (char*)d_ws;

  int*   counts = (int*)ws;                         // 16 ints @0
  int*   gfirst = (int*)(ws + 64);                  // 18 ints
  int*   desc   = (int*)(ws + 256);                 // 142 ints
  int*   sel    = (int*)(ws + 1024);                // 8192 ints
  float* wslot  = (float*)(ws + 33792);             // 16384 f32
  int*   lists  = (int*)(ws + 99328);               // 2*8*8192 ints -> end 623616

  hipLaunchKernelGGL(gating_kernel, dim3(512), dim3(256), 0, stream,
                     x, Wg, bg, sel, wslot);
  hipLaunchKernelGGL(build_lists_kernel, dim3(16), dim3(256), 0, stream,
                     sel, counts, lists);
  hipLaunchKernelGGL(build_desc_kernel, dim3(1), dim3(64), 0, stream,
                     counts, gfirst, desc);

  dim3 ggrid(HID / 256, 39);   // x = ntile fastest; max 39 256-row tiles per slot
  hipLaunchKernelGGL((moe_gemm_f32<0>), ggrid, dim3(512), 0, stream,
                     x, We, be, counts, gfirst, desc, lists, wslot, out);
  hipLaunchKernelGGL((moe_gemm_f32<1>), ggrid, dim3(512), 0, stream,
                     x, We, be, counts, gfirst, desc, lists, wslot, out);
}

// Round 15
// 471.529 us; speedup vs baseline: 1.3576x; 1.1712x over previous
//
#include <hip/hip_runtime.h>

#define N_TOK 8192
#define DIM   2048
#define HID   2048
#define NE    8
#define BK    64
#define NKT   (DIM / BK)

typedef unsigned short u16;
typedef __attribute__((ext_vector_type(4))) float f4v;
typedef __attribute__((ext_vector_type(8))) short s8v;

__device__ __forceinline__ unsigned int cvtpk(float lo, float hi) {
  unsigned int r;
  asm volatile("v_cvt_pk_bf16_f32 %0, %1, %2" : "=v"(r) : "v"(lo), "v"(hi));
  return r;
}

// ---------------- gating: logits -> softmax -> top2 (NO atomics) ----------------
__global__ __launch_bounds__(256) void gating_kernel(
    const float* __restrict__ x, const float* __restrict__ Wg,
    const float* __restrict__ bg, int* __restrict__ sel,
    float* __restrict__ wslot)
{
  __shared__ float wg_lds[NE][DIM];   // 64 KB
  #pragma unroll
  for (int i = 0; i < 16; ++i) {
    int f = threadIdx.x + 256 * i;          // float4 index 0..4095
    int d = f >> 1, ep = (f & 1) * 4;
    float4 w = reinterpret_cast<const float4*>(Wg)[f];
    wg_lds[ep + 0][d] = w.x; wg_lds[ep + 1][d] = w.y;
    wg_lds[ep + 2][d] = w.z; wg_lds[ep + 3][d] = w.w;
  }
  __syncthreads();

  int wave = threadIdx.x >> 6, lane = threadIdx.x & 63;
  #pragma unroll 2
  for (int j = 0; j < 4; ++j) {
    int n = blockIdx.x * 16 + wave * 4 + j;
    const float4* x4 = reinterpret_cast<const float4*>(x + (size_t)n * DIM);
    float acc[NE] = {0.f,0.f,0.f,0.f,0.f,0.f,0.f,0.f};
    #pragma unroll
    for (int i = 0; i < 8; ++i) {
      int d4 = lane + 64 * i;
      float4 xv = x4[d4];
      #pragma unroll
      for (int e = 0; e < NE; ++e) {
        float4 w = *reinterpret_cast<const float4*>(&wg_lds[e][d4 * 4]);
        acc[e] += xv.x * w.x + xv.y * w.y + xv.z * w.z + xv.w * w.w;
      }
    }
    #pragma unroll
    for (int e = 0; e < NE; ++e)
      #pragma unroll
      for (int off = 32; off; off >>= 1)
        acc[e] += __shfl_xor(acc[e], off);

    if (lane == 0) {
      float m = -1e30f;
      #pragma unroll
      for (int e = 0; e < NE; ++e) { acc[e] += bg[e]; m = fmaxf(m, acc[e]); }
      float p[NE]; float s = 0.f;
      #pragma unroll
      for (int e = 0; e < NE; ++e) { p[e] = expf(acc[e] - m); s += p[e]; }
      float inv = 1.0f / s;
      int e1 = 0; float v1 = p[0];
      #pragma unroll
      for (int e = 1; e < NE; ++e) if (p[e] > v1) { v1 = p[e]; e1 = e; }
      int e2 = -1; float v2 = -1.f;
      #pragma unroll
      for (int e = 0; e < NE; ++e) if (e != e1 && p[e] > v2) { v2 = p[e]; e2 = e; }
      sel[n] = e1 | (e2 << 4);
      wslot[n] = v1 * inv;
      wslot[N_TOK + n] = v2 * inv;
    }
  }
}

// ---------------- build per-(slot,expert) token lists: deterministic compaction ----------------
__global__ __launch_bounds__(256) void build_lists_kernel(
    const int* __restrict__ sel, int* __restrict__ counts, int* __restrict__ lists)
{
  __shared__ int wsum[4];
  __shared__ int runbase;
  int b = blockIdx.x;           // 0..15: slot = b>>3, expert = b&7
  int s = b >> 3, e = b & 7;
  int t = threadIdx.x, lane = t & 63, wave = t >> 6;
  if (t == 0) runbase = 0;
  __syncthreads();
  int* listp = lists + (size_t)b * N_TOK;
  for (int base = 0; base < N_TOK; base += 256) {
    int n = base + t;
    int sv = sel[n];
    int field = s ? (sv >> 4) : (sv & 15);
    bool p = (field == e);
    unsigned long long mask = __ballot(p);
    int rank = __popcll(mask & ((1ull << lane) - 1ull));
    int wtot = __popcll(mask);
    if (lane == 0) wsum[wave] = wtot;
    __syncthreads();
    int wbase = 0;
    #pragma unroll
    for (int w = 0; w < 4; ++w) wbase += (w < wave) ? wsum[w] : 0;
    int tot = wsum[0] + wsum[1] + wsum[2] + wsum[3];
    if (p) listp[runbase + wbase + rank] = n;
    __syncthreads();
    if (t == 0) runbase += tot;
    __syncthreads();
  }
  if (t == 0) counts[b] = runbase;
}

// ---------------- build compact tile descriptors ----------------
__global__ void build_desc_kernel(const int* __restrict__ counts,
                                  int* __restrict__ gfirst, int* __restrict__ desc)
{
  if (threadIdx.x == 0 && blockIdx.x == 0) {
    for (int s = 0; s < 2; ++s) {
      int tc = 0;
      for (int e = 0; e < NE; ++e) {
        gfirst[s * 9 + e] = tc;
        int nt = (counts[s * NE + e] + 127) >> 7;
        for (int i = 0; i < nt; ++i) desc[s * 71 + tc++] = (e << 8) | i;
      }
      gfirst[s * 9 + 8] = tc;
    }
  }
}

// ---------------- GEMM core ----------------
__device__ __forceinline__ void mma_step(const u16* A_lds, const u16* B_lds,
                                         int lane, int wm, int wn, f4v acc[4][4])
{
  int lrow = lane & 15, lkg = lane >> 4;
  #pragma unroll
  for (int kk2 = 0; kk2 < 2; ++kk2) {
    s8v a[4], b[4];
    unsigned int koff = (unsigned int)(kk2 * 64 + lkg * 16);
    #pragma unroll
    for (int i = 0; i < 4; ++i) {
      unsigned int arow = (unsigned int)(wm + i * 16 + lrow);
      a[i] = *reinterpret_cast<const s8v*>(
          reinterpret_cast<const char*>(A_lds) + ((arow * 128u + koff) ^ ((arow & 7u) << 4)));
      unsigned int brow = (unsigned int)(wn + i * 16 + lrow);
      b[i] = *reinterpret_cast<const s8v*>(
          reinterpret_cast<const char*>(B_lds) + ((brow * 128u + koff) ^ ((brow & 7u) << 4)));
    }
    #pragma unroll
    for (int mi = 0; mi < 4; ++mi)
      #pragma unroll
      for (int ni = 0; ni < 4; ++ni)
        acc[mi][ni] = __builtin_amdgcn_mfma_f32_16x16x32_bf16(a[mi], b[ni], acc[mi][ni], 0, 0, 0);
  }
}

// R3 exact structure + single-barrier dbuf pipeline:
//   issue L(kt+1) -> mma(buf kt&1) -> write buf[(kt+1)&1] -> ONE barrier.
// Loads get the whole MFMA cluster of flight; no mid-loop drain-to-zero stall.
template <int PHASE>
__global__ __launch_bounds__(256) void moe_gemm_f32(
    const float* __restrict__ xf, const float* __restrict__ Wef,
    const float* __restrict__ be, const int* __restrict__ counts,
    const int* __restrict__ gfirst, const int* __restrict__ desc,
    const int* __restrict__ lists, const float* __restrict__ wslot,
    float* __restrict__ out)
{
  __shared__ __align__(16) u16 A_lds[2][128 * 64];
  __shared__ __align__(16) u16 B_lds[2][128 * 64];
  __shared__ int   tok_lds[128];
  __shared__ float wgt_lds[128];

  const int ntile = blockIdx.x;          // 0..15 (fastest; XCD = ntile&7 pins B panels)
  const int idx   = blockIdx.y;          // 0..70
  if (idx >= gfirst[PHASE * 9 + 8]) return;
  const int d  = desc[PHASE * 71 + idx];
  const int e  = d >> 8;
  const int mt = d & 255;
  const int cnt = counts[PHASE * NE + e];

  const int t = threadIdx.x;
  if (t < 128) {
    int r = mt * 128 + t;
    int rc = (r < cnt) ? r : (cnt - 1);
    int tok = lists[(PHASE * NE + e) * N_TOK + rc];
    tok_lds[t] = tok;
    wgt_lds[t] = wslot[PHASE * N_TOK + tok];
  }
  __syncthreads();

  const int lane = t & 63, wid = t >> 6;
  const int wm = (wid & 1) * 64, wn = (wid >> 1) * 64;

  f4v acc[4][4];
  f4v zero = {0.f, 0.f, 0.f, 0.f};
  #pragma unroll
  for (int mi = 0; mi < 4; ++mi)
    #pragma unroll
    for (int ni = 0; ni < 4; ++ni) acc[mi][ni] = zero;

  const float* wef = Wef + (size_t)e * DIM * HID;
  const float* ap[8]; unsigned int ab[8];
  #pragma unroll
  for (int i = 0; i < 8; ++i) {
    int flat = t + 256 * i;             // 0..2047
    int row = flat >> 4, c4 = flat & 15;
    ap[i] = xf + (size_t)tok_lds[row] * DIM + c4 * 4;
    ab[i] = ((unsigned int)(row * 128 + c4 * 8)) ^ (((unsigned int)row & 7u) << 4);
  }
  const int bn = t & 127, bh = t >> 7;
  const float* bp0 = wef + (size_t)(bh * 32) * HID + ntile * 128 + bn;
  unsigned int bbyte[8];
  #pragma unroll
  for (int kb = 0; kb < 8; ++kb)
    bbyte[kb] = ((unsigned int)(bn * 128 + bh * 64 + kb * 8)) ^ (((unsigned int)bn & 7u) << 4);

  float4 av[8];
  float  bv[32];

#define LOAD_REGS(KT) do {                                                      \
    _Pragma("unroll") for (int i = 0; i < 8; ++i)                               \
      av[i] = *reinterpret_cast<const float4*>(ap[i] + (KT) * 64);              \
    const float* bpk = bp0 + (size_t)(KT) * 64 * HID;                           \
    _Pragma("unroll") for (int kb = 0; kb < 8; ++kb) {                          \
      _Pragma("unroll") for (int r = 0; r < 4; ++r)                             \
        bv[kb * 4 + r] = bpk[(size_t)(kb * 4 + r) * HID];                       \
    }                                                                           \
  } while (0)

#define WRITE_LDS(BUF) do {                                                     \
    char* abase = reinterpret_cast<char*>(&A_lds[BUF][0]);                      \
    char* bbase = reinterpret_cast<char*>(&B_lds[BUF][0]);                      \
    _Pragma("unroll") for (int i = 0; i < 8; ++i) {                             \
      uint2 w; w.x = cvtpk(av[i].x, av[i].y); w.y = cvtpk(av[i].z, av[i].w);    \
      *reinterpret_cast<uint2*>(abase + ab[i]) = w;                             \
    }                                                                           \
    _Pragma("unroll") for (int kb = 0; kb < 8; ++kb) {                          \
      uint2 w; w.x = cvtpk(bv[kb*4+0], bv[kb*4+1]);                             \
               w.y = cvtpk(bv[kb*4+2], bv[kb*4+3]);                             \
      *reinterpret_cast<uint2*>(bbase + bbyte[kb]) = w;                         \
    }                                                                           \
  } while (0)

  // prologue: tile 0 into buf0
  LOAD_REGS(0);
  WRITE_LDS(0);
  __syncthreads();

  #pragma unroll 1
  for (int kt = 0; kt < NKT; ++kt) {
    if (kt + 1 < NKT) LOAD_REGS(kt + 1);   // issue: in flight across the MFMA cluster
    asm volatile("" ::: "memory");         // pin loads before the mma cluster
    __builtin_amdgcn_s_setprio(1);
    mma_step(&A_lds[kt & 1][0], &B_lds[kt & 1][0], lane, wm, wn, acc);
    __builtin_amdgcn_s_setprio(0);
    if (kt + 1 < NKT) WRITE_LDS((kt + 1) & 1);  // counted vmcnt waits here, after mma
    __syncthreads();
    // WAR-safe: a wave writes buf[(kt+1)&1] only after the end-of-(kt-1) barrier,
    // which guarantees no wave is still reading that parity (proof in journal).
  }

#undef LOAD_REGS
#undef WRITE_LDS

  // epilogue: D row=(lane>>4)*4+q (A/m), col=lane&15 (B/n)  [m89-verified]
  const float* bev = be + (size_t)e * HID + ntile * 128;
  #pragma unroll
  for (int ni = 0; ni < 4; ++ni) {
    int col = wn + ni * 16 + (lane & 15);
    float bevv = bev[col];
    #pragma unroll
    for (int mi = 0; mi < 4; ++mi) {
      #pragma unroll
      for (int q = 0; q < 4; ++q) {
        int row = wm + mi * 16 + (lane >> 4) * 4 + q;
        if (mt * 128 + row < cnt) {
          int tok = tok_lds[row];
          float w = wgt_lds[row];
          float v = w * (acc[mi][ni][q] + bevv);
          float* o = out + (size_t)tok * HID + ntile * 128 + col;
          if (PHASE == 0) *o = v; else *o += v;
        }
      }
    }
  }
}

// ---------------- host ----------------
extern "C" void kernel_launch(void* const* d_in, const int* in_sizes, int n_in,
                              void* d_out, int out_size, void* d_ws, size_t ws_size,
                              hipStream_t stream) {
  const float* x  = (const float*)d_in[0];
  const float* Wg = (const float*)d_in[1];
  const float* bg = (const float*)d_in[2];
  const float* We = (const float*)d_in[3];
  const float* be = (const float*)d_in[4];
  float* out = (float*)d_out;
  char* ws = (char*)d_ws;

  int*   counts = (int*)ws;                         // 16 ints @0
  int*   gfirst = (int*)(ws + 64);                  // 18 ints
  int*   desc   = (int*)(ws + 256);                 // 142 ints
  int*   sel    = (int*)(ws + 1024);                // 8192 ints
  float* wslot  = (float*)(ws + 33792);             // 16384 f32
  int*   lists  = (int*)(ws + 99328);               // 2*8*8192 ints -> end 623616

  hipLaunchKernelGGL(gating_kernel, dim3(512), dim3(256), 0, stream,
                     x, Wg, bg, sel, wslot);
  hipLaunchKernelGGL(build_lists_kernel, dim3(16), dim3(256), 0, stream,
                     sel, counts, lists);
  hipLaunchKernelGGL(build_desc_kernel, dim3(1), dim3(64), 0, stream,
                     counts, gfirst, desc);

  dim3 ggrid(16, 71);   // x = ntile fastest: XCD-pinned B panels + R3 pacing
  hipLaunchKernelGGL((moe_gemm_f32<0>), ggrid, dim3(256), 0, stream,
                     x, We, be, counts, gfirst, desc, lists, wslot, out);
  hipLaunchKernelGGL((moe_gemm_f32<1>), ggrid, dim3(256), 0, stream,
                     x, We, be, counts, gfirst, desc, lists, wslot, out);
}